// Round 24
// baseline (123.687 us; speedup 1.0000x reference)
//
#include <hip/hip_runtime.h>
#include <hip/hip_bf16.h>
#include <stdint.h>

#define DEVI __device__ __forceinline__

using bf16 = __hip_bfloat16;
typedef __bf16 bf16x8 __attribute__((ext_vector_type(8)));
typedef float f32x4 __attribute__((ext_vector_type(4)));
typedef float f32x16 __attribute__((ext_vector_type(16)));
typedef int i32x2 __attribute__((ext_vector_type(2)));

static constexpr int Bb = 2, Nn = 2048, Cc = 1024, Hh = 16, Dd = 64;
static constexpr float CSC = 0.125f * 1.44269504088896340736f;  // scale*log2(e)

DEVI bf16 f2bf(float x) { __bf16 h = (__bf16)x; return *(bf16*)&h; }
DEVI float fexp2(float x) { return __builtin_amdgcn_exp2f(x); }

DEVI bf16x8 cvt8(f32x4 a, f32x4 b) {
  bf16x8 r;
  r[0] = (__bf16)a[0]; r[1] = (__bf16)a[1]; r[2] = (__bf16)a[2]; r[3] = (__bf16)a[3];
  r[4] = (__bf16)b[0]; r[5] = (__bf16)b[1]; r[6] = (__bf16)b[2]; r[7] = (__bf16)b[3];
  return r;
}

DEVI uint32_t pk2(float a, float b) {   // fuses to v_cvt_pk_bf16_f32
  __bf16 x = (__bf16)a, y = (__bf16)b;
  uint16_t ux = *(uint16_t*)&x, uy = *(uint16_t*)&y;
  return (uint32_t)ux | ((uint32_t)uy << 16);
}

DEVI bf16x8 mk8(uint32_t a, uint32_t b, uint32_t c, uint32_t d) {
  union { uint32_t u[4]; bf16x8 v; } x;
  x.u[0] = a; x.u[1] = b; x.u[2] = c; x.u[3] = d;
  return x.v;
}

// async global->LDS, 16B/lane; LDS dest = wave-uniform base + lane*16
DEVI void gld_lds16(const bf16* g, bf16* l) {
  __builtin_amdgcn_global_load_lds(
      (__attribute__((address_space(1))) void*)(g),
      (__attribute__((address_space(3))) void*)(l),
      16, 0, 0);
}

// ---------------------------------------------------------------------------
// f32 -> bf16 pre-convert: x(2048 blks) + wq/wk/wv/wp(512 blks each) = 4096.
// ---------------------------------------------------------------------------
__global__ __launch_bounds__(256) void k_cvt(const float* __restrict__ x,
                                             const float* __restrict__ wq,
                                             const float* __restrict__ wk,
                                             const float* __restrict__ wv,
                                             const float* __restrict__ wp,
                                             bf16* xb, bf16* wqb, bf16* wkb,
                                             bf16* wvb, bf16* wpb) {
  int bid = blockIdx.x;
  const float* src; bf16* dst; size_t off;
  if (bid < 2048) {
    src = x; dst = xb; off = (size_t)bid * 2048;
  } else {
    int s = (bid - 2048) >> 9, r = (bid - 2048) & 511;
    off = (size_t)r * 2048;
    src = s == 0 ? wq : s == 1 ? wk : s == 2 ? wv : wp;
    dst = s == 0 ? wqb : s == 1 ? wkb : s == 2 ? wvb : wpb;
  }
  size_t i = off + (size_t)threadIdx.x * 8;
  f32x4 a = *(const f32x4*)(src + i);
  f32x4 b = *(const f32x4*)(src + i + 4);
  *(bf16x8*)(dst + i) = cvt8(a, b);
}

// ---------------------------------------------------------------------------
// bf16 GEMM, global_load_lds staging, m97 2-barrier structure (r8-proven).
// out[m][n] = sum_k A[m][k]*B[n][k]; BM=MFC*32, BN=128, BK=32; 256 thr.
// ---------------------------------------------------------------------------
template <int MFC, class Epi>
DEVI void gemm_lds_body(const bf16* __restrict__ A, const bf16* __restrict__ Bw,
                        int K, int m0, int n0, bf16* lA, bf16* lB, Epi epi) {
  constexpr int BM = MFC * 32;
  constexpr int PA = BM / 64;          // A 16B-chunks per thread
  const int t = threadIdx.x;
  const int lane = t & 63, wave = t >> 6;
  const int wr = wave >> 1, wc = wave & 1;

  f32x4 acc[MFC][4] = {};

  for (int k0 = 0; k0 < K; k0 += 32) {
    __syncthreads();                   // prev compute done, LDS free
#pragma unroll
    for (int p = 0; p < PA; ++p) {
      int c = p * 256 + t;
      int row = c >> 2, col = (c & 3) * 8;
      gld_lds16(A + (size_t)(m0 + row) * K + k0 + col,
                lA + (size_t)(p * 256 + wave * 64) * 8);
    }
#pragma unroll
    for (int p = 0; p < 2; ++p) {
      int c = p * 256 + t;
      int row = c >> 2, col = (c & 3) * 8;
      gld_lds16(Bw + (size_t)(n0 + row) * K + k0 + col,
                lB + (size_t)(p * 256 + wave * 64) * 8);
    }
    __syncthreads();                   // drains vmcnt -> tile ready

    bf16x8 aF[MFC];
#pragma unroll
    for (int mf = 0; mf < MFC; ++mf)
      aF[mf] = *(const bf16x8*)(lA + (wr * (BM / 2) + mf * 16 + (lane & 15)) * 32 + (lane >> 4) * 8);
#pragma unroll
    for (int nf = 0; nf < 4; ++nf) {
      bf16x8 bF = *(const bf16x8*)(lB + (wc * 64 + nf * 16 + (lane & 15)) * 32 + (lane >> 4) * 8);
#pragma unroll
      for (int mf = 0; mf < MFC; ++mf)
        acc[mf][nf] = __builtin_amdgcn_mfma_f32_16x16x32_bf16(aF[mf], bF, acc[mf][nf], 0, 0, 0);
    }
  }

#pragma unroll
  for (int mf = 0; mf < MFC; ++mf)
#pragma unroll
    for (int nf = 0; nf < 4; ++nf)
#pragma unroll
      for (int r = 0; r < 4; ++r) {
        int gm = m0 + wr * (BM / 2) + mf * 16 + (lane >> 4) * 4 + r;
        int gn = n0 + wc * 64 + nf * 16 + (lane & 15);
        epi(gm, gn, acc[mf][nf][r]);
      }
}

// Epilogues -----------------------------------------------------------------
struct EpiRope {  // rows=(b,n), cols=(h,d); RoPE (+opt scale) -> bf16 (b,h,n,d)
  bf16* dst; const float* cosw; const float* sinw; float scale;
  DEVI void operator()(int gm, int gn, float v) const {
    int b = gm >> 11, n = gm & 2047;
    int h = gn >> 6, d = gn & 63;
    int i = d >> 1;
    float c = cosw[n * 32 + i], s = sinw[n * 32 + i];
    float p = __shfl_xor(v, 1);
    float o = (d & 1) ? (p * s + v * c) : (v * c - p * s);
    dst[((size_t)(b * Hh + h) * Nn + n) * 64 + d] = f2bf(o * scale);
  }
};

struct EpiVt {  // rows=c=(h,d), cols=(b,n); -> bf16 (b,h,d,n)
  bf16* dst;
  DEVI void operator()(int gm, int gn, float v) const {
    int h = gm >> 6, d = gm & 63;
    int b = gn >> 11, n = gn & 2047;
    dst[((size_t)(b * Hh + h) * 64 + d) * Nn + n] = f2bf(v);
  }
};

struct EpiProj {  // rows=(b,n), cols=c; +bias -> f32 row-major
  float* dst; const float* bias;
  DEVI void operator()(int gm, int gn, float v) const {
    dst[(size_t)gm * Cc + gn] = v + bias[gn];
  }
};

// Fused QKV: 768 blocks, XCD-clustered by x-panel (r16-proven).
__global__ __launch_bounds__(256) void k_qkv(const bf16* __restrict__ xb,
                                             const bf16* __restrict__ wqb,
                                             const bf16* __restrict__ wkb,
                                             const bf16* __restrict__ wvb,
                                             bf16* q_ws, bf16* k_ws, bf16* vt_ws,
                                             const float* __restrict__ cw,
                                             const float* __restrict__ sw) {
  __shared__ __align__(16) bf16 smem[256 * 32];
  bf16* lA = smem;
  bf16* lB = smem + 128 * 32;
  int bid = blockIdx.x;
  if (bid < 512) {
    int sub = bid & 255;
    int c = sub & 7, rest = sub >> 3;
    int m0 = (c + 8 * (rest & 3)) * 128;   // x panel (m%8 == bid%8)
    int n0 = (rest >> 2) * 128;
    bool isq = bid < 256;
    gemm_lds_body<4>(xb, isq ? wqb : wkb, Cc, m0, n0, lA, lB,
                     EpiRope{isq ? q_ws : k_ws, cw, sw, isq ? CSC : 1.0f});
  } else {
    int sub = bid - 512;
    int c = sub & 7, rest = sub >> 3;
    int n0 = (c + 8 * (rest & 3)) * 128;   // x panel (n%8 == bid%8)
    int m0 = (rest >> 2) * 128;            // wv rows
    gemm_lds_body<4>(wvb, xb, Cc, m0, n0, lA, lB, EpiVt{vt_ws});
  }
}

// Proj: BM=64 -> grid (64,8).
__global__ __launch_bounds__(256) void k_proj(const bf16* __restrict__ A,
                                              const bf16* __restrict__ W,
                                              float* dst, const float* __restrict__ bias) {
  __shared__ __align__(16) bf16 smem[192 * 32];
  gemm_lds_body<2>(A, W, Cc, blockIdx.x * 64, blockIdx.y * 128,
                   smem, smem + 64 * 32, EpiProj{dst, bias});
}

// ---------------------------------------------------------------------------
// Flash (decoupled barrier groups): 512 blocks x 256 thr (4 waves, 2 blk/CU);
// wave owns 32 q rows as ONE 32x32 block; block q-tile 128; KV tile 128 -> 16
// iterations. Two independent blocks per CU so one block's barrier drain
// overlaps the other's compute. 32x32 MFMA, swapped QK^T, in-register P via
// cvt_pk + permlane32_swap. DMA double-buffer with pre-swizzled source;
// XCD-clustered bh. No max tracking (log2 domain, Q pre-scaled).
// ---------------------------------------------------------------------------
__global__ __launch_bounds__(256) void k_flash(const bf16* __restrict__ q_ws,
                                               const bf16* __restrict__ k_ws,
                                               const bf16* __restrict__ vt_ws,
                                               bf16* __restrict__ attn_o) {
  __shared__ __align__(16) bf16 lK[2][128 * 64];
  __shared__ __align__(16) bf16 lV[2][64 * 128];

  const int t = threadIdx.x, lane = t & 63, wave = t >> 6;
  const int l31 = lane & 31, hi = lane >> 5;
  const int bid = blockIdx.x;
  const int slot = bid >> 3;                    // [0,64) per XCD class
  const int bh = (bid & 7) * 4 + (slot >> 4);   // 4 bh per XCD, 16 blocks/bh
  const int q0w = (slot & 15) * 128 + wave * 32; // 128 q-rows per block
  const bf16* qg = q_ws + (size_t)bh * Nn * 64;
  const bf16* kg = k_ws + (size_t)bh * Nn * 64;
  const bf16* vg = vt_ws + (size_t)bh * 64 * Nn;

  // Q B-frags: lane holds Q[q = q0w + l31][d = kd*16 + hi*8 + j]
  bf16x8 qF[4];
#pragma unroll
  for (int kd = 0; kd < 4; ++kd)
    qF[kd] = *(const bf16x8*)(qg + (size_t)(q0w + l31) * 64 + kd * 16 + hi * 8);

  f32x16 accO[2] = {};                 // [d0]
  float Ls4[4] = {};                   // chain-split lane-partial sums

  // stage 128-kv tile: K 128x64 (1024 chunks), V 64x128 (1024 chunks);
  // 256 thr -> 4 K-chunks + 4 V-chunks per thread.
  auto stage_tile = [&](int kt, int buf) {
#pragma unroll
    for (int p = 0; p < 4; ++p) {
      int c = p * 256 + t;
      int krow = c >> 3, kch = (c & 7) ^ (krow & 7);
      gld_lds16(kg + (size_t)(kt * 128 + krow) * 64 + kch * 8,
                lK[buf] + (size_t)(p * 256 + wave * 64) * 8);
      int vrow = c >> 4, vch = (c & 15) ^ (vrow & 7);
      gld_lds16(vg + (size_t)vrow * Nn + kt * 128 + vch * 8,
                lV[buf] + (size_t)(p * 256 + wave * 64) * 8);
    }
  };

  stage_tile(0, 0);
  __syncthreads();

  constexpr int NT = Nn / 128;         // 16
  for (int kt = 0; kt < NT; ++kt) {
    const int cur = kt & 1;
    if (kt + 1 < NT) stage_tile(kt + 1, cur ^ 1);  // DMA into idle buffer

#pragma unroll
    for (int kb = 0; kb < 4; ++kb) {   // kv-block of 32
      // S^T = K Q^T : lane holds S[kv local=(r&3)+8*(r>>2)+4*hi][q=l31]
      f32x16 accT = {};
      __builtin_amdgcn_s_setprio(1);
#pragma unroll
      for (int kd = 0; kd < 4; ++kd) {
        int row = kb * 32 + l31;
        int ch = (kd * 2 + hi) ^ (row & 7);
        bf16x8 kF = *(const bf16x8*)(lK[cur] + row * 64 + ch * 8);
        accT = __builtin_amdgcn_mfma_f32_32x32x16_bf16(kF, qF[kd], accT, 0, 0, 0);
      }
      __builtin_amdgcn_s_setprio(0);

      // P = exp2(S^T), chain-split lane-local row sums, pack to bf16
      float p[16];
#pragma unroll
      for (int r = 0; r < 16; ++r) { p[r] = fexp2(accT[r]); Ls4[r & 3] += p[r]; }

      uint32_t c01 = pk2(p[0], p[1]),  c23 = pk2(p[2], p[3]);
      uint32_t c89 = pk2(p[4], p[5]),  cab = pk2(p[6], p[7]);
      uint32_t d01 = pk2(p[8], p[9]),  d23 = pk2(p[10], p[11]);
      uint32_t d89 = pk2(p[12], p[13]), dab = pk2(p[14], p[15]);
      i32x2 s0a = __builtin_amdgcn_permlane32_swap((int)c01, (int)c89, false, false);
      i32x2 s0b = __builtin_amdgcn_permlane32_swap((int)c23, (int)cab, false, false);
      i32x2 s1a = __builtin_amdgcn_permlane32_swap((int)d01, (int)d89, false, false);
      i32x2 s1b = __builtin_amdgcn_permlane32_swap((int)d23, (int)dab, false, false);
      bf16x8 paF[2] = { mk8(s0a[0], s0b[0], s0a[1], s0b[1]),
                        mk8(s1a[0], s1b[0], s1a[1], s1b[1]) };

      // O += P V : B-frag from lV (V^T rows d), col chunk = kb*4 + s*2 + hi
      __builtin_amdgcn_s_setprio(1);
#pragma unroll
      for (int d0 = 0; d0 < 2; ++d0)
#pragma unroll
        for (int s = 0; s < 2; ++s) {
          int vrow = d0 * 32 + l31;
          int ch = (kb * 4 + s * 2 + hi) ^ (vrow & 7);
          bf16x8 vF = *(const bf16x8*)(lV[cur] + vrow * 128 + ch * 8);
          accO[d0] = __builtin_amdgcn_mfma_f32_32x32x16_bf16(paF[s], vF, accO[d0], 0, 0, 0);
        }
      __builtin_amdgcn_s_setprio(0);
    }

    __syncthreads();                   // drains DMA; next buffer ready
  }

  // full row sum for q = l31 (other half holds complementary kv slots)
  float L = (Ls4[0] + Ls4[1]) + (Ls4[2] + Ls4[3]);
  L += __shfl_xor(L, 32);

  // store O: D[row=q=(r&3)+8*(r>>2)+4*hi][col=d=d0*32+l31]
  const int b = bh >> 4, h = bh & 15;
#pragma unroll
  for (int r = 0; r < 16; ++r) {
    int ql = (r & 3) + 8 * (r >> 2) + 4 * hi;
    float inv = 1.0f / __shfl(L, ql);
    int qrow = q0w + ql;
#pragma unroll
    for (int d0 = 0; d0 < 2; ++d0) {
      int d = d0 * 32 + l31;
      attn_o[((size_t)(b * Nn + qrow)) * Cc + h * 64 + d] = f2bf(accO[d0][r] * inv);
    }
  }
}

// ---------------------------------------------------------------------------
extern "C" void kernel_launch(void* const* d_in, const int* in_sizes, int n_in,
                              void* d_out, int out_size, void* d_ws, size_t ws_size,
                              hipStream_t stream) {
  (void)in_sizes; (void)n_in; (void)out_size; (void)ws_size;
  const float* x  = (const float*)d_in[0];
  const float* wq = (const float*)d_in[1];
  const float* wk = (const float*)d_in[2];
  const float* wv = (const float*)d_in[3];
  const float* wp = (const float*)d_in[4];
  const float* bp = (const float*)d_in[5];
  const float* cw = (const float*)d_in[6];
  const float* sw = (const float*)d_in[7];
  float* out = (float*)d_out;

  const size_t M1 = 1u << 20;           // 1M elems
  bf16* x_bf  = (bf16*)d_ws;            // 4M  (reused as ao_ws after qkv)
  bf16* wq_bf = x_bf + 4 * M1;          // 1M
  bf16* wk_bf = wq_bf + M1;             // 1M
  bf16* wv_bf = wk_bf + M1;             // 1M
  bf16* wp_bf = wv_bf + M1;             // 1M
  bf16* q_ws  = wp_bf + M1;             // 4M
  bf16* k_ws  = q_ws + 4 * M1;          // 4M
  bf16* vt_ws = k_ws + 4 * M1;          // 4M  -> total 20M elems = 40 MB
  bf16* ao_ws = x_bf;                   // overlay: x_bf dead after k_qkv

  k_cvt  <<<dim3(4096),    dim3(256), 0, stream>>>(x, wq, wk, wv, wp,
                                                   x_bf, wq_bf, wk_bf, wv_bf, wp_bf);
  k_qkv  <<<dim3(768),     dim3(256), 0, stream>>>(x_bf, wq_bf, wk_bf, wv_bf,
                                                   q_ws, k_ws, vt_ws, cw, sw);
  k_flash<<<dim3(512),     dim3(256), 0, stream>>>(q_ws, k_ws, vt_ws, ao_ws);
  k_proj <<<dim3(64, 8),   dim3(256), 0, stream>>>(ao_ws, wp_bf, out, bp);
}

// Round 25
// 118.855 us; speedup vs baseline: 1.0407x; 1.0407x over previous
//
#include <hip/hip_runtime.h>
#include <hip/hip_bf16.h>
#include <stdint.h>

#define DEVI __device__ __forceinline__

using bf16 = __hip_bfloat16;
typedef __bf16 bf16x8 __attribute__((ext_vector_type(8)));
typedef float f32x4 __attribute__((ext_vector_type(4)));
typedef float f32x16 __attribute__((ext_vector_type(16)));
typedef int i32x2 __attribute__((ext_vector_type(2)));

static constexpr int Bb = 2, Nn = 2048, Cc = 1024, Hh = 16, Dd = 64;
static constexpr float CSC = 0.125f * 1.44269504088896340736f;  // scale*log2(e)

DEVI bf16 f2bf(float x) { __bf16 h = (__bf16)x; return *(bf16*)&h; }
DEVI float fexp2(float x) { return __builtin_amdgcn_exp2f(x); }

DEVI bf16x8 cvt8(f32x4 a, f32x4 b) {
  bf16x8 r;
  r[0] = (__bf16)a[0]; r[1] = (__bf16)a[1]; r[2] = (__bf16)a[2]; r[3] = (__bf16)a[3];
  r[4] = (__bf16)b[0]; r[5] = (__bf16)b[1]; r[6] = (__bf16)b[2]; r[7] = (__bf16)b[3];
  return r;
}

DEVI uint32_t pk2(float a, float b) {   // fuses to v_cvt_pk_bf16_f32
  __bf16 x = (__bf16)a, y = (__bf16)b;
  uint16_t ux = *(uint16_t*)&x, uy = *(uint16_t*)&y;
  return (uint32_t)ux | ((uint32_t)uy << 16);
}

DEVI bf16x8 mk8(uint32_t a, uint32_t b, uint32_t c, uint32_t d) {
  union { uint32_t u[4]; bf16x8 v; } x;
  x.u[0] = a; x.u[1] = b; x.u[2] = c; x.u[3] = d;
  return x.v;
}

// async global->LDS, 16B/lane; LDS dest = wave-uniform base + lane*16
DEVI void gld_lds16(const bf16* g, bf16* l) {
  __builtin_amdgcn_global_load_lds(
      (__attribute__((address_space(1))) void*)(g),
      (__attribute__((address_space(3))) void*)(l),
      16, 0, 0);
}

// ---------------------------------------------------------------------------
// f32 -> bf16 pre-convert: x(2048 blks) + wq/wk/wv/wp(512 blks each) = 4096.
// ---------------------------------------------------------------------------
__global__ __launch_bounds__(256) void k_cvt(const float* __restrict__ x,
                                             const float* __restrict__ wq,
                                             const float* __restrict__ wk,
                                             const float* __restrict__ wv,
                                             const float* __restrict__ wp,
                                             bf16* xb, bf16* wqb, bf16* wkb,
                                             bf16* wvb, bf16* wpb) {
  int bid = blockIdx.x;
  const float* src; bf16* dst; size_t off;
  if (bid < 2048) {
    src = x; dst = xb; off = (size_t)bid * 2048;
  } else {
    int s = (bid - 2048) >> 9, r = (bid - 2048) & 511;
    off = (size_t)r * 2048;
    src = s == 0 ? wq : s == 1 ? wk : s == 2 ? wv : wp;
    dst = s == 0 ? wqb : s == 1 ? wkb : s == 2 ? wvb : wpb;
  }
  size_t i = off + (size_t)threadIdx.x * 8;
  f32x4 a = *(const f32x4*)(src + i);
  f32x4 b = *(const f32x4*)(src + i + 4);
  *(bf16x8*)(dst + i) = cvt8(a, b);
}

// ---------------------------------------------------------------------------
// bf16 GEMM, global_load_lds staging, m97 2-barrier structure (r8-proven).
// out[m][n] = sum_k A[m][k]*B[n][k]; BM=MFC*32, BN=128, BK=32; 256 thr.
// ---------------------------------------------------------------------------
template <int MFC, class Epi>
DEVI void gemm_lds_body(const bf16* __restrict__ A, const bf16* __restrict__ Bw,
                        int K, int m0, int n0, bf16* lA, bf16* lB, Epi epi) {
  constexpr int BM = MFC * 32;
  constexpr int PA = BM / 64;          // A 16B-chunks per thread
  const int t = threadIdx.x;
  const int lane = t & 63, wave = t >> 6;
  const int wr = wave >> 1, wc = wave & 1;

  f32x4 acc[MFC][4] = {};

  for (int k0 = 0; k0 < K; k0 += 32) {
    __syncthreads();                   // prev compute done, LDS free
#pragma unroll
    for (int p = 0; p < PA; ++p) {
      int c = p * 256 + t;
      int row = c >> 2, col = (c & 3) * 8;
      gld_lds16(A + (size_t)(m0 + row) * K + k0 + col,
                lA + (size_t)(p * 256 + wave * 64) * 8);
    }
#pragma unroll
    for (int p = 0; p < 2; ++p) {
      int c = p * 256 + t;
      int row = c >> 2, col = (c & 3) * 8;
      gld_lds16(Bw + (size_t)(n0 + row) * K + k0 + col,
                lB + (size_t)(p * 256 + wave * 64) * 8);
    }
    __syncthreads();                   // drains vmcnt -> tile ready

    bf16x8 aF[MFC];
#pragma unroll
    for (int mf = 0; mf < MFC; ++mf)
      aF[mf] = *(const bf16x8*)(lA + (wr * (BM / 2) + mf * 16 + (lane & 15)) * 32 + (lane >> 4) * 8);
#pragma unroll
    for (int nf = 0; nf < 4; ++nf) {
      bf16x8 bF = *(const bf16x8*)(lB + (wc * 64 + nf * 16 + (lane & 15)) * 32 + (lane >> 4) * 8);
#pragma unroll
      for (int mf = 0; mf < MFC; ++mf)
        acc[mf][nf] = __builtin_amdgcn_mfma_f32_16x16x32_bf16(aF[mf], bF, acc[mf][nf], 0, 0, 0);
    }
  }

#pragma unroll
  for (int mf = 0; mf < MFC; ++mf)
#pragma unroll
    for (int nf = 0; nf < 4; ++nf)
#pragma unroll
      for (int r = 0; r < 4; ++r) {
        int gm = m0 + wr * (BM / 2) + mf * 16 + (lane >> 4) * 4 + r;
        int gn = n0 + wc * 64 + nf * 16 + (lane & 15);
        epi(gm, gn, acc[mf][nf][r]);
      }
}

// Epilogues -----------------------------------------------------------------
struct EpiRope {  // rows=(b,n), cols=(h,d); RoPE (+opt scale) -> bf16 (b,h,n,d)
  bf16* dst; const float* cosw; const float* sinw; float scale;
  DEVI void operator()(int gm, int gn, float v) const {
    int b = gm >> 11, n = gm & 2047;
    int h = gn >> 6, d = gn & 63;
    int i = d >> 1;
    float c = cosw[n * 32 + i], s = sinw[n * 32 + i];
    float p = __shfl_xor(v, 1);
    float o = (d & 1) ? (p * s + v * c) : (v * c - p * s);
    dst[((size_t)(b * Hh + h) * Nn + n) * 64 + d] = f2bf(o * scale);
  }
};

struct EpiVt {  // rows=c=(h,d), cols=(b,n); -> bf16 (b,h,d,n)
  bf16* dst;
  DEVI void operator()(int gm, int gn, float v) const {
    int h = gm >> 6, d = gm & 63;
    int b = gn >> 11, n = gn & 2047;
    dst[((size_t)(b * Hh + h) * 64 + d) * Nn + n] = f2bf(v);
  }
};

struct EpiProj {  // rows=(b,n), cols=c; +bias -> f32 row-major
  float* dst; const float* bias;
  DEVI void operator()(int gm, int gn, float v) const {
    dst[(size_t)gm * Cc + gn] = v + bias[gn];
  }
};

// Fused QKV: 768 blocks, XCD-clustered by x-panel (r16-proven).
__global__ __launch_bounds__(256) void k_qkv(const bf16* __restrict__ xb,
                                             const bf16* __restrict__ wqb,
                                             const bf16* __restrict__ wkb,
                                             const bf16* __restrict__ wvb,
                                             bf16* q_ws, bf16* k_ws, bf16* vt_ws,
                                             const float* __restrict__ cw,
                                             const float* __restrict__ sw) {
  __shared__ __align__(16) bf16 smem[256 * 32];
  bf16* lA = smem;
  bf16* lB = smem + 128 * 32;
  int bid = blockIdx.x;
  if (bid < 512) {
    int sub = bid & 255;
    int c = sub & 7, rest = sub >> 3;
    int m0 = (c + 8 * (rest & 3)) * 128;   // x panel (m%8 == bid%8)
    int n0 = (rest >> 2) * 128;
    bool isq = bid < 256;
    gemm_lds_body<4>(xb, isq ? wqb : wkb, Cc, m0, n0, lA, lB,
                     EpiRope{isq ? q_ws : k_ws, cw, sw, isq ? CSC : 1.0f});
  } else {
    int sub = bid - 512;
    int c = sub & 7, rest = sub >> 3;
    int n0 = (c + 8 * (rest & 3)) * 128;   // x panel (n%8 == bid%8)
    int m0 = (rest >> 2) * 128;            // wv rows
    gemm_lds_body<4>(wvb, xb, Cc, m0, n0, lA, lB, EpiVt{vt_ws});
  }
}

// Proj: BM=64 -> grid (64,8).
__global__ __launch_bounds__(256) void k_proj(const bf16* __restrict__ A,
                                              const bf16* __restrict__ W,
                                              float* dst, const float* __restrict__ bias) {
  __shared__ __align__(16) bf16 smem[192 * 32];
  gemm_lds_body<2>(A, W, Cc, blockIdx.x * 64, blockIdx.y * 128,
                   smem, smem + 64 * 32, EpiProj{dst, bias});
}

// ---------------------------------------------------------------------------
// Flash (r20/r21/r23-proven): 256 blocks x 512 thr (8 waves, 1 block/CU);
// wave owns 32 q rows as ONE 32x32 block; block q-tile 256; KV tile 128 ->
// 16 iterations. 32x32 MFMA, swapped QK^T, in-register P via cvt_pk +
// permlane32_swap. DMA double-buffer with pre-swizzled source; XCD-clustered
// bh. No max tracking (log2 domain, Q pre-scaled).
// ---------------------------------------------------------------------------
__global__ __launch_bounds__(512) void k_flash(const bf16* __restrict__ q_ws,
                                               const bf16* __restrict__ k_ws,
                                               const bf16* __restrict__ vt_ws,
                                               bf16* __restrict__ attn_o) {
  __shared__ __align__(16) bf16 lK[2][128 * 64];
  __shared__ __align__(16) bf16 lV[2][64 * 128];

  const int t = threadIdx.x, lane = t & 63, wave = t >> 6;
  const int l31 = lane & 31, hi = lane >> 5;
  const int bid = blockIdx.x;
  const int slot = bid >> 3;                    // [0,32) per XCD class
  const int bh = (bid & 7) * 4 + (slot >> 3);   // 4 bh per XCD
  const int q0w = (slot & 7) * 256 + wave * 32; // 256 q-rows per block
  const bf16* qg = q_ws + (size_t)bh * Nn * 64;
  const bf16* kg = k_ws + (size_t)bh * Nn * 64;
  const bf16* vg = vt_ws + (size_t)bh * 64 * Nn;

  // Q B-frags: lane holds Q[q = q0w + l31][d = kd*16 + hi*8 + j]
  bf16x8 qF[4];
#pragma unroll
  for (int kd = 0; kd < 4; ++kd)
    qF[kd] = *(const bf16x8*)(qg + (size_t)(q0w + l31) * 64 + kd * 16 + hi * 8);

  f32x16 accO[2] = {};                 // [d0]
  float Ls4[4] = {};                   // chain-split lane-partial sums

  // stage 128-kv tile: K 128x64 (1024 chunks), V 64x128 (1024 chunks);
  // 512 thr -> 2 K-chunks + 2 V-chunks per thread.
  auto stage_tile = [&](int kt, int buf) {
#pragma unroll
    for (int p = 0; p < 2; ++p) {
      int c = p * 512 + t;
      int krow = c >> 3, kch = (c & 7) ^ (krow & 7);
      gld_lds16(kg + (size_t)(kt * 128 + krow) * 64 + kch * 8,
                lK[buf] + (size_t)(p * 512 + wave * 64) * 8);
      int vrow = c >> 4, vch = (c & 15) ^ (vrow & 7);
      gld_lds16(vg + (size_t)vrow * Nn + kt * 128 + vch * 8,
                lV[buf] + (size_t)(p * 512 + wave * 64) * 8);
    }
  };

  stage_tile(0, 0);
  __syncthreads();

  constexpr int NT = Nn / 128;         // 16
  for (int kt = 0; kt < NT; ++kt) {
    const int cur = kt & 1;
    if (kt + 1 < NT) stage_tile(kt + 1, cur ^ 1);  // DMA into idle buffer

#pragma unroll
    for (int kb = 0; kb < 4; ++kb) {   // kv-block of 32
      // S^T = K Q^T : lane holds S[kv local=(r&3)+8*(r>>2)+4*hi][q=l31]
      f32x16 accT = {};
      __builtin_amdgcn_s_setprio(1);
#pragma unroll
      for (int kd = 0; kd < 4; ++kd) {
        int row = kb * 32 + l31;
        int ch = (kd * 2 + hi) ^ (row & 7);
        bf16x8 kF = *(const bf16x8*)(lK[cur] + row * 64 + ch * 8);
        accT = __builtin_amdgcn_mfma_f32_32x32x16_bf16(kF, qF[kd], accT, 0, 0, 0);
      }
      __builtin_amdgcn_s_setprio(0);

      // P = exp2(S^T), chain-split lane-local row sums, pack to bf16
      float p[16];
#pragma unroll
      for (int r = 0; r < 16; ++r) { p[r] = fexp2(accT[r]); Ls4[r & 3] += p[r]; }

      uint32_t c01 = pk2(p[0], p[1]),  c23 = pk2(p[2], p[3]);
      uint32_t c89 = pk2(p[4], p[5]),  cab = pk2(p[6], p[7]);
      uint32_t d01 = pk2(p[8], p[9]),  d23 = pk2(p[10], p[11]);
      uint32_t d89 = pk2(p[12], p[13]), dab = pk2(p[14], p[15]);
      i32x2 s0a = __builtin_amdgcn_permlane32_swap((int)c01, (int)c89, false, false);
      i32x2 s0b = __builtin_amdgcn_permlane32_swap((int)c23, (int)cab, false, false);
      i32x2 s1a = __builtin_amdgcn_permlane32_swap((int)d01, (int)d89, false, false);
      i32x2 s1b = __builtin_amdgcn_permlane32_swap((int)d23, (int)dab, false, false);
      bf16x8 paF[2] = { mk8(s0a[0], s0b[0], s0a[1], s0b[1]),
                        mk8(s1a[0], s1b[0], s1a[1], s1b[1]) };

      // O += P V : B-frag from lV (V^T rows d), col chunk = kb*4 + s*2 + hi
      __builtin_amdgcn_s_setprio(1);
#pragma unroll
      for (int d0 = 0; d0 < 2; ++d0)
#pragma unroll
        for (int s = 0; s < 2; ++s) {
          int vrow = d0 * 32 + l31;
          int ch = (kb * 4 + s * 2 + hi) ^ (vrow & 7);
          bf16x8 vF = *(const bf16x8*)(lV[cur] + vrow * 128 + ch * 8);
          accO[d0] = __builtin_amdgcn_mfma_f32_32x32x16_bf16(paF[s], vF, accO[d0], 0, 0, 0);
        }
      __builtin_amdgcn_s_setprio(0);
    }

    __syncthreads();                   // drains DMA; next buffer ready
  }

  // full row sum for q = l31 (other half holds complementary kv slots)
  float L = (Ls4[0] + Ls4[1]) + (Ls4[2] + Ls4[3]);
  L += __shfl_xor(L, 32);

  // store O: D[row=q=(r&3)+8*(r>>2)+4*hi][col=d=d0*32+l31]
  const int b = bh >> 4, h = bh & 15;
#pragma unroll
  for (int r = 0; r < 16; ++r) {
    int ql = (r & 3) + 8 * (r >> 2) + 4 * hi;
    float inv = 1.0f / __shfl(L, ql);
    int qrow = q0w + ql;
#pragma unroll
    for (int d0 = 0; d0 < 2; ++d0) {
      int d = d0 * 32 + l31;
      attn_o[((size_t)(b * Nn + qrow)) * Cc + h * 64 + d] = f2bf(accO[d0][r] * inv);
    }
  }
}

// ---------------------------------------------------------------------------
extern "C" void kernel_launch(void* const* d_in, const int* in_sizes, int n_in,
                              void* d_out, int out_size, void* d_ws, size_t ws_size,
                              hipStream_t stream) {
  (void)in_sizes; (void)n_in; (void)out_size; (void)ws_size;
  const float* x  = (const float*)d_in[0];
  const float* wq = (const float*)d_in[1];
  const float* wk = (const float*)d_in[2];
  const float* wv = (const float*)d_in[3];
  const float* wp = (const float*)d_in[4];
  const float* bp = (const float*)d_in[5];
  const float* cw = (const float*)d_in[6];
  const float* sw = (const float*)d_in[7];
  float* out = (float*)d_out;

  const size_t M1 = 1u << 20;           // 1M elems
  bf16* x_bf  = (bf16*)d_ws;            // 4M  (reused as ao_ws after qkv)
  bf16* wq_bf = x_bf + 4 * M1;          // 1M
  bf16* wk_bf = wq_bf + M1;             // 1M
  bf16* wv_bf = wk_bf + M1;             // 1M
  bf16* wp_bf = wv_bf + M1;             // 1M
  bf16* q_ws  = wp_bf + M1;             // 4M
  bf16* k_ws  = q_ws + 4 * M1;          // 4M
  bf16* vt_ws = k_ws + 4 * M1;          // 4M  -> total 20M elems = 40 MB
  bf16* ao_ws = x_bf;                   // overlay: x_bf dead after k_qkv

  k_cvt  <<<dim3(4096),    dim3(256), 0, stream>>>(x, wq, wk, wv, wp,
                                                   x_bf, wq_bf, wk_bf, wv_bf, wp_bf);
  k_qkv  <<<dim3(768),     dim3(256), 0, stream>>>(x_bf, wq_bf, wk_bf, wv_bf,
                                                   q_ws, k_ws, vt_ws, cw, sw);
  k_flash<<<dim3(256),     dim3(512), 0, stream>>>(q_ws, k_ws, vt_ws, ao_ws);
  k_proj <<<dim3(64, 8),   dim3(256), 0, stream>>>(ao_ws, wp_bf, out, bp);
}

// Round 26
// 118.572 us; speedup vs baseline: 1.0431x; 1.0024x over previous
//
#include <hip/hip_runtime.h>
#include <hip/hip_bf16.h>
#include <stdint.h>

#define DEVI __device__ __forceinline__

using bf16 = __hip_bfloat16;
typedef __bf16 bf16x8 __attribute__((ext_vector_type(8)));
typedef float f32x4 __attribute__((ext_vector_type(4)));
typedef float f32x16 __attribute__((ext_vector_type(16)));
typedef int i32x2 __attribute__((ext_vector_type(2)));

static constexpr int Bb = 2, Nn = 2048, Cc = 1024, Hh = 16, Dd = 64;
static constexpr float CSC = 0.125f * 1.44269504088896340736f;  // scale*log2(e)

DEVI bf16 f2bf(float x) { __bf16 h = (__bf16)x; return *(bf16*)&h; }
DEVI float fexp2(float x) { return __builtin_amdgcn_exp2f(x); }

DEVI bf16x8 cvt8(f32x4 a, f32x4 b) {
  bf16x8 r;
  r[0] = (__bf16)a[0]; r[1] = (__bf16)a[1]; r[2] = (__bf16)a[2]; r[3] = (__bf16)a[3];
  r[4] = (__bf16)b[0]; r[5] = (__bf16)b[1]; r[6] = (__bf16)b[2]; r[7] = (__bf16)b[3];
  return r;
}

DEVI uint32_t pk2(float a, float b) {   // fuses to v_cvt_pk_bf16_f32
  __bf16 x = (__bf16)a, y = (__bf16)b;
  uint16_t ux = *(uint16_t*)&x, uy = *(uint16_t*)&y;
  return (uint32_t)ux | ((uint32_t)uy << 16);
}

DEVI bf16x8 mk8(uint32_t a, uint32_t b, uint32_t c, uint32_t d) {
  union { uint32_t u[4]; bf16x8 v; } x;
  x.u[0] = a; x.u[1] = b; x.u[2] = c; x.u[3] = d;
  return x.v;
}

// async global->LDS, 16B/lane; LDS dest = wave-uniform base + lane*16
DEVI void gld_lds16(const bf16* g, bf16* l) {
  __builtin_amdgcn_global_load_lds(
      (__attribute__((address_space(1))) void*)(g),
      (__attribute__((address_space(3))) void*)(l),
      16, 0, 0);
}

// ---------------------------------------------------------------------------
// f32 -> bf16 pre-convert: x(2048 blks) + wq/wk/wv/wp(512 blks each) = 4096.
// ---------------------------------------------------------------------------
__global__ __launch_bounds__(256) void k_cvt(const float* __restrict__ x,
                                             const float* __restrict__ wq,
                                             const float* __restrict__ wk,
                                             const float* __restrict__ wv,
                                             const float* __restrict__ wp,
                                             bf16* xb, bf16* wqb, bf16* wkb,
                                             bf16* wvb, bf16* wpb) {
  int bid = blockIdx.x;
  const float* src; bf16* dst; size_t off;
  if (bid < 2048) {
    src = x; dst = xb; off = (size_t)bid * 2048;
  } else {
    int s = (bid - 2048) >> 9, r = (bid - 2048) & 511;
    off = (size_t)r * 2048;
    src = s == 0 ? wq : s == 1 ? wk : s == 2 ? wv : wp;
    dst = s == 0 ? wqb : s == 1 ? wkb : s == 2 ? wvb : wpb;
  }
  size_t i = off + (size_t)threadIdx.x * 8;
  f32x4 a = *(const f32x4*)(src + i);
  f32x4 b = *(const f32x4*)(src + i + 4);
  *(bf16x8*)(dst + i) = cvt8(a, b);
}

// ---------------------------------------------------------------------------
// bf16 GEMM, global_load_lds staging, m97 2-barrier structure (r8-proven).
// out[m][n] = sum_k A[m][k]*B[n][k]; BM=MFC*32, BN=128, BK=32; 256 thr.
// ---------------------------------------------------------------------------
template <int MFC, class Epi>
DEVI void gemm_lds_body(const bf16* __restrict__ A, const bf16* __restrict__ Bw,
                        int K, int m0, int n0, bf16* lA, bf16* lB, Epi epi) {
  constexpr int BM = MFC * 32;
  constexpr int PA = BM / 64;          // A 16B-chunks per thread
  const int t = threadIdx.x;
  const int lane = t & 63, wave = t >> 6;
  const int wr = wave >> 1, wc = wave & 1;

  f32x4 acc[MFC][4] = {};

  for (int k0 = 0; k0 < K; k0 += 32) {
    __syncthreads();                   // prev compute done, LDS free
#pragma unroll
    for (int p = 0; p < PA; ++p) {
      int c = p * 256 + t;
      int row = c >> 2, col = (c & 3) * 8;
      gld_lds16(A + (size_t)(m0 + row) * K + k0 + col,
                lA + (size_t)(p * 256 + wave * 64) * 8);
    }
#pragma unroll
    for (int p = 0; p < 2; ++p) {
      int c = p * 256 + t;
      int row = c >> 2, col = (c & 3) * 8;
      gld_lds16(Bw + (size_t)(n0 + row) * K + k0 + col,
                lB + (size_t)(p * 256 + wave * 64) * 8);
    }
    __syncthreads();                   // drains vmcnt -> tile ready

    bf16x8 aF[MFC];
#pragma unroll
    for (int mf = 0; mf < MFC; ++mf)
      aF[mf] = *(const bf16x8*)(lA + (wr * (BM / 2) + mf * 16 + (lane & 15)) * 32 + (lane >> 4) * 8);
#pragma unroll
    for (int nf = 0; nf < 4; ++nf) {
      bf16x8 bF = *(const bf16x8*)(lB + (wc * 64 + nf * 16 + (lane & 15)) * 32 + (lane >> 4) * 8);
#pragma unroll
      for (int mf = 0; mf < MFC; ++mf)
        acc[mf][nf] = __builtin_amdgcn_mfma_f32_16x16x32_bf16(aF[mf], bF, acc[mf][nf], 0, 0, 0);
    }
  }

#pragma unroll
  for (int mf = 0; mf < MFC; ++mf)
#pragma unroll
    for (int nf = 0; nf < 4; ++nf)
#pragma unroll
      for (int r = 0; r < 4; ++r) {
        int gm = m0 + wr * (BM / 2) + mf * 16 + (lane >> 4) * 4 + r;
        int gn = n0 + wc * 64 + nf * 16 + (lane & 15);
        epi(gm, gn, acc[mf][nf][r]);
      }
}

// Epilogues -----------------------------------------------------------------
struct EpiRope {  // rows=(b,n), cols=(h,d); RoPE (+opt scale) -> bf16 (b,h,n,d)
  bf16* dst; const float* cosw; const float* sinw; float scale;
  DEVI void operator()(int gm, int gn, float v) const {
    int b = gm >> 11, n = gm & 2047;
    int h = gn >> 6, d = gn & 63;
    int i = d >> 1;
    float c = cosw[n * 32 + i], s = sinw[n * 32 + i];
    float p = __shfl_xor(v, 1);
    float o = (d & 1) ? (p * s + v * c) : (v * c - p * s);
    dst[((size_t)(b * Hh + h) * Nn + n) * 64 + d] = f2bf(o * scale);
  }
};

struct EpiVt {  // rows=c=(h,d), cols=(b,n); -> bf16 (b,h,d,n)
  bf16* dst;
  DEVI void operator()(int gm, int gn, float v) const {
    int h = gm >> 6, d = gm & 63;
    int b = gn >> 11, n = gn & 2047;
    dst[((size_t)(b * Hh + h) * 64 + d) * Nn + n] = f2bf(v);
  }
};

struct EpiProj {  // rows=(b,n), cols=c; +bias -> f32 row-major
  float* dst; const float* bias;
  DEVI void operator()(int gm, int gn, float v) const {
    dst[(size_t)gm * Cc + gn] = v + bias[gn];
  }
};

// Fused QKV: 768 blocks, XCD-clustered by x-panel (r16-proven).
__global__ __launch_bounds__(256) void k_qkv(const bf16* __restrict__ xb,
                                             const bf16* __restrict__ wqb,
                                             const bf16* __restrict__ wkb,
                                             const bf16* __restrict__ wvb,
                                             bf16* q_ws, bf16* k_ws, bf16* vt_ws,
                                             const float* __restrict__ cw,
                                             const float* __restrict__ sw) {
  __shared__ __align__(16) bf16 smem[256 * 32];
  bf16* lA = smem;
  bf16* lB = smem + 128 * 32;
  int bid = blockIdx.x;
  if (bid < 512) {
    int sub = bid & 255;
    int c = sub & 7, rest = sub >> 3;
    int m0 = (c + 8 * (rest & 3)) * 128;   // x panel (m%8 == bid%8)
    int n0 = (rest >> 2) * 128;
    bool isq = bid < 256;
    gemm_lds_body<4>(xb, isq ? wqb : wkb, Cc, m0, n0, lA, lB,
                     EpiRope{isq ? q_ws : k_ws, cw, sw, isq ? CSC : 1.0f});
  } else {
    int sub = bid - 512;
    int c = sub & 7, rest = sub >> 3;
    int n0 = (c + 8 * (rest & 3)) * 128;   // x panel (n%8 == bid%8)
    int m0 = (rest >> 2) * 128;            // wv rows
    gemm_lds_body<4>(wvb, xb, Cc, m0, n0, lA, lB, EpiVt{vt_ws});
  }
}

// Proj: BM=64 -> grid (64,8).
__global__ __launch_bounds__(256) void k_proj(const bf16* __restrict__ A,
                                              const bf16* __restrict__ W,
                                              float* dst, const float* __restrict__ bias) {
  __shared__ __align__(16) bf16 smem[192 * 32];
  gemm_lds_body<2>(A, W, Cc, blockIdx.x * 64, blockIdx.y * 128,
                   smem, smem + 64 * 32, EpiProj{dst, bias});
}

// ---------------------------------------------------------------------------
// Flash (r23 + 4-bit V swizzle): 256 blocks x 512 thr (8 waves, 1 block/CU);
// wave owns 32 q rows as ONE 32x32 block; block q-tile 256; KV tile 128 ->
// 16 iterations. 32x32 MFMA, swapped QK^T, in-register P via cvt_pk +
// permlane32_swap. DMA double-buffer with pre-swizzled source; XCD-clustered
// bh. V chunk swizzle widened to ^(vrow&15): 16-chunk rows give 4 XOR bits,
// reducing V-frag reads from 4-way to 2-way (free) bank aliasing.
// No max tracking (log2 domain, Q pre-scaled).
// ---------------------------------------------------------------------------
__global__ __launch_bounds__(512) void k_flash(const bf16* __restrict__ q_ws,
                                               const bf16* __restrict__ k_ws,
                                               const bf16* __restrict__ vt_ws,
                                               bf16* __restrict__ attn_o) {
  __shared__ __align__(16) bf16 lK[2][128 * 64];
  __shared__ __align__(16) bf16 lV[2][64 * 128];

  const int t = threadIdx.x, lane = t & 63, wave = t >> 6;
  const int l31 = lane & 31, hi = lane >> 5;
  const int bid = blockIdx.x;
  const int slot = bid >> 3;                    // [0,32) per XCD class
  const int bh = (bid & 7) * 4 + (slot >> 3);   // 4 bh per XCD
  const int q0w = (slot & 7) * 256 + wave * 32; // 256 q-rows per block
  const bf16* qg = q_ws + (size_t)bh * Nn * 64;
  const bf16* kg = k_ws + (size_t)bh * Nn * 64;
  const bf16* vg = vt_ws + (size_t)bh * 64 * Nn;

  // Q B-frags: lane holds Q[q = q0w + l31][d = kd*16 + hi*8 + j]
  bf16x8 qF[4];
#pragma unroll
  for (int kd = 0; kd < 4; ++kd)
    qF[kd] = *(const bf16x8*)(qg + (size_t)(q0w + l31) * 64 + kd * 16 + hi * 8);

  f32x16 accO[2] = {};                 // [d0]
  float Ls4[4] = {};                   // chain-split lane-partial sums

  // stage 128-kv tile: K 128x64 (1024 chunks), V 64x128 (1024 chunks);
  // 512 thr -> 2 K-chunks + 2 V-chunks per thread.
  auto stage_tile = [&](int kt, int buf) {
#pragma unroll
    for (int p = 0; p < 2; ++p) {
      int c = p * 512 + t;
      int krow = c >> 3, kch = (c & 7) ^ (krow & 7);
      gld_lds16(kg + (size_t)(kt * 128 + krow) * 64 + kch * 8,
                lK[buf] + (size_t)(p * 512 + wave * 64) * 8);
      int vrow = c >> 4, vch = (c & 15) ^ (vrow & 15);  // 4-bit V swizzle
      gld_lds16(vg + (size_t)vrow * Nn + kt * 128 + vch * 8,
                lV[buf] + (size_t)(p * 512 + wave * 64) * 8);
    }
  };

  stage_tile(0, 0);
  __syncthreads();

  constexpr int NT = Nn / 128;         // 16
  for (int kt = 0; kt < NT; ++kt) {
    const int cur = kt & 1;
    if (kt + 1 < NT) stage_tile(kt + 1, cur ^ 1);  // DMA into idle buffer

#pragma unroll
    for (int kb = 0; kb < 4; ++kb) {   // kv-block of 32
      // S^T = K Q^T : lane holds S[kv local=(r&3)+8*(r>>2)+4*hi][q=l31]
      f32x16 accT = {};
      __builtin_amdgcn_s_setprio(1);
#pragma unroll
      for (int kd = 0; kd < 4; ++kd) {
        int row = kb * 32 + l31;
        int ch = (kd * 2 + hi) ^ (row & 7);
        bf16x8 kF = *(const bf16x8*)(lK[cur] + row * 64 + ch * 8);
        accT = __builtin_amdgcn_mfma_f32_32x32x16_bf16(kF, qF[kd], accT, 0, 0, 0);
      }
      __builtin_amdgcn_s_setprio(0);

      // P = exp2(S^T), chain-split lane-local row sums, pack to bf16
      float p[16];
#pragma unroll
      for (int r = 0; r < 16; ++r) { p[r] = fexp2(accT[r]); Ls4[r & 3] += p[r]; }

      uint32_t c01 = pk2(p[0], p[1]),  c23 = pk2(p[2], p[3]);
      uint32_t c89 = pk2(p[4], p[5]),  cab = pk2(p[6], p[7]);
      uint32_t d01 = pk2(p[8], p[9]),  d23 = pk2(p[10], p[11]);
      uint32_t d89 = pk2(p[12], p[13]), dab = pk2(p[14], p[15]);
      i32x2 s0a = __builtin_amdgcn_permlane32_swap((int)c01, (int)c89, false, false);
      i32x2 s0b = __builtin_amdgcn_permlane32_swap((int)c23, (int)cab, false, false);
      i32x2 s1a = __builtin_amdgcn_permlane32_swap((int)d01, (int)d89, false, false);
      i32x2 s1b = __builtin_amdgcn_permlane32_swap((int)d23, (int)dab, false, false);
      bf16x8 paF[2] = { mk8(s0a[0], s0b[0], s0a[1], s0b[1]),
                        mk8(s1a[0], s1b[0], s1a[1], s1b[1]) };

      // O += P V : B-frag from lV (V^T rows d), col chunk = kb*4 + s*2 + hi
      __builtin_amdgcn_s_setprio(1);
#pragma unroll
      for (int d0 = 0; d0 < 2; ++d0)
#pragma unroll
        for (int s = 0; s < 2; ++s) {
          int vrow = d0 * 32 + l31;
          int ch = (kb * 4 + s * 2 + hi) ^ (vrow & 15);  // 4-bit V swizzle
          bf16x8 vF = *(const bf16x8*)(lV[cur] + vrow * 128 + ch * 8);
          accO[d0] = __builtin_amdgcn_mfma_f32_32x32x16_bf16(paF[s], vF, accO[d0], 0, 0, 0);
        }
      __builtin_amdgcn_s_setprio(0);
    }

    __syncthreads();                   // drains DMA; next buffer ready
  }

  // full row sum for q = l31 (other half holds complementary kv slots)
  float L = (Ls4[0] + Ls4[1]) + (Ls4[2] + Ls4[3]);
  L += __shfl_xor(L, 32);

  // store O: D[row=q=(r&3)+8*(r>>2)+4*hi][col=d=d0*32+l31]
  const int b = bh >> 4, h = bh & 15;
#pragma unroll
  for (int r = 0; r < 16; ++r) {
    int ql = (r & 3) + 8 * (r >> 2) + 4 * hi;
    float inv = 1.0f / __shfl(L, ql);
    int qrow = q0w + ql;
#pragma unroll
    for (int d0 = 0; d0 < 2; ++d0) {
      int d = d0 * 32 + l31;
      attn_o[((size_t)(b * Nn + qrow)) * Cc + h * 64 + d] = f2bf(accO[d0][r] * inv);
    }
  }
}

// ---------------------------------------------------------------------------
extern "C" void kernel_launch(void* const* d_in, const int* in_sizes, int n_in,
                              void* d_out, int out_size, void* d_ws, size_t ws_size,
                              hipStream_t stream) {
  (void)in_sizes; (void)n_in; (void)out_size; (void)ws_size;
  const float* x  = (const float*)d_in[0];
  const float* wq = (const float*)d_in[1];
  const float* wk = (const float*)d_in[2];
  const float* wv = (const float*)d_in[3];
  const float* wp = (const float*)d_in[4];
  const float* bp = (const float*)d_in[5];
  const float* cw = (const float*)d_in[6];
  const float* sw = (const float*)d_in[7];
  float* out = (float*)d_out;

  const size_t M1 = 1u << 20;           // 1M elems
  bf16* x_bf  = (bf16*)d_ws;            // 4M  (reused as ao_ws after qkv)
  bf16* wq_bf = x_bf + 4 * M1;          // 1M
  bf16* wk_bf = wq_bf + M1;             // 1M
  bf16* wv_bf = wk_bf + M1;             // 1M
  bf16* wp_bf = wv_bf + M1;             // 1M
  bf16* q_ws  = wp_bf + M1;             // 4M
  bf16* k_ws  = q_ws + 4 * M1;          // 4M
  bf16* vt_ws = k_ws + 4 * M1;          // 4M  -> total 20M elems = 40 MB
  bf16* ao_ws = x_bf;                   // overlay: x_bf dead after k_qkv

  k_cvt  <<<dim3(4096),    dim3(256), 0, stream>>>(x, wq, wk, wv, wp,
                                                   x_bf, wq_bf, wk_bf, wv_bf, wp_bf);
  k_qkv  <<<dim3(768),     dim3(256), 0, stream>>>(x_bf, wq_bf, wk_bf, wv_bf,
                                                   q_ws, k_ws, vt_ws, cw, sw);
  k_flash<<<dim3(256),     dim3(512), 0, stream>>>(q_ws, k_ws, vt_ws, ao_ws);
  k_proj <<<dim3(64, 8),   dim3(256), 0, stream>>>(ao_ws, wp_bf, out, bp);
}